// Round 11
// baseline (192.966 us; speedup 1.0000x reference)
//
#include <hip/hip_runtime.h>
#include <hip/hip_bf16.h>

#define NSEN 4000
#define NP   4096
#define DIN  128
#define DOUT 128
#define EDIM 16
#define BATCH 8

typedef __attribute__((ext_vector_type(8))) short bf16x8;
typedef __attribute__((ext_vector_type(4))) float f32x4;

__device__ __forceinline__ unsigned short f2bf(float f) {
  unsigned int u = __float_as_uint(f);
  unsigned int r = (u + 0x7FFFu + ((u >> 16) & 1u)) >> 16;
  return (unsigned short)r;
}
__device__ __forceinline__ float bf2f(unsigned short s) {
  unsigned int u = ((unsigned int)s) << 16;
  return __uint_as_float(u);
}

__device__ __forceinline__ void gl_lds16(const void* g, void* l) {
  __builtin_amdgcn_global_load_lds((const __attribute__((address_space(1))) void*)g,
                                   (__attribute__((address_space(3))) void*)l, 16, 0, 0);
}

// ---------------- Kernel 1 (merged prep) -----------------------------------------
// blocks 0..249:   P = exp(relu(E1 @ E2^T)) unnorm -> adjp bf16 ; rinv = 1/rowsum.
//                  block 0 also zeroes the split-K flags (poison-safe init).
// blocks 250..505: yt[b*128+o][m] = bf16( (x @ W)[b,m,o] ), cols m>=NSEN -> 0.
//                  W staged in LDS; output bounced through LDS for coalesced stores.
__global__ __launch_bounds__(512) void k_prep(const float* __restrict__ E1,
                                              const float* __restrict__ E2,
                                              const float* __restrict__ W,
                                              const float* __restrict__ x,
                                              unsigned short* __restrict__ adjp,
                                              float* __restrict__ rinv,
                                              unsigned short* __restrict__ yt,
                                              int* __restrict__ flags) {
  __shared__ float rsum[8][16];
  __shared__ unsigned short wlds[128 * 136];  // W^T bf16 [o][f]
  __shared__ unsigned short ylds[128 * 136];  // y^T bf16 [o][m_local]
  const int bx = blockIdx.x;
  const int tid = threadIdx.x;
  const int lane = tid & 63, wv = tid >> 6;
  const int lr = lane & 15, lq = lane >> 4;

  if (bx >= 250) {
    // ---- stage W -> LDS as bf16 W^T (coalesced float4 reads, 8/thread) ----
    {
      const int fr = tid >> 5;   // 0..15
      const int o4 = tid & 31;   // 0..31
#pragma unroll
      for (int r8 = 0; r8 < 8; r8++) {
        const int f = fr + r8 * 16;
        float4 w4 = *(const float4*)&W[(size_t)f * DOUT + o4 * 4];
        wlds[(o4 * 4 + 0) * 136 + f] = f2bf(w4.x);
        wlds[(o4 * 4 + 1) * 136 + f] = f2bf(w4.y);
        wlds[(o4 * 4 + 2) * 136 + f] = f2bf(w4.z);
        wlds[(o4 * 4 + 3) * 136 + f] = f2bf(w4.w);
      }
    }
    __syncthreads();

    // ---- y^T GEMM: block -> (batch b, 128-m chunk) ----
    const int yi = bx - 250;        // 0..255
    const int b  = yi >> 5;         // 0..7
    const int m0 = (yi & 31) * 128; // 0..3968
    const int mh = wv >> 2;         // 0..1 : 64-m half
    const int os = wv & 3;          // 0..3 : 32-o strip

    bf16x8 af[2][4];  // [ot][ks] : A-frags = W^T[o][f] from LDS
#pragma unroll
    for (int ot = 0; ot < 2; ot++) {
      const int ob = os * 32 + ot * 16 + lr;
#pragma unroll
      for (int ks = 0; ks < 4; ks++)
        af[ot][ks] = *(const bf16x8*)&wlds[ob * 136 + ks * 32 + lq * 8];
    }

#pragma unroll
    for (int mt = 0; mt < 4; mt++) {
      const int mloc = mh * 64 + mt * 16;
      const int m = m0 + mloc + lr;
      bf16x8 bx8[4];
      if (m < NSEN) {
        const float* xp = &x[((size_t)b * NSEN + m) * DIN + lq * 8];
#pragma unroll
        for (int ks = 0; ks < 4; ks++) {
          float4 v0 = *(const float4*)(xp + ks * 32);
          float4 v1 = *(const float4*)(xp + ks * 32 + 4);
          bx8[ks][0] = (short)f2bf(v0.x); bx8[ks][1] = (short)f2bf(v0.y);
          bx8[ks][2] = (short)f2bf(v0.z); bx8[ks][3] = (short)f2bf(v0.w);
          bx8[ks][4] = (short)f2bf(v1.x); bx8[ks][5] = (short)f2bf(v1.y);
          bx8[ks][6] = (short)f2bf(v1.z); bx8[ks][7] = (short)f2bf(v1.w);
        }
      } else {
#pragma unroll
        for (int ks = 0; ks < 4; ks++)
#pragma unroll
          for (int j = 0; j < 8; j++) bx8[ks][j] = 0;
      }
#pragma unroll
      for (int ot = 0; ot < 2; ot++) {
        f32x4 c = (f32x4){0.f, 0.f, 0.f, 0.f};
#pragma unroll
        for (int ks = 0; ks < 4; ks++)
          c = __builtin_amdgcn_mfma_f32_16x16x32_bf16(af[ot][ks], bx8[ks], c, 0, 0, 0);
        // C: col = lr (m-local), row = lq*4+i (o-local) -> LDS bounce
#pragma unroll
        for (int i = 0; i < 4; i++)
          ylds[(os * 32 + ot * 16 + lq * 4 + i) * 136 + mloc + lr] = f2bf(c[i]);
      }
    }
    __syncthreads();
    // coalesced store: 128 o-rows x 16 8-m chunks = 2048 chunks, 4/thread
#pragma unroll
    for (int s2 = 0; s2 < 4; s2++) {
      int c = s2 * 512 + tid;
      int row = c >> 4;          // 0..127
      int mc = c & 15;           // 0..15
      *(bf16x8*)&yt[(size_t)(b * 128 + row) * NP + m0 + mc * 8] =
          *(const bf16x8*)&ylds[row * 136 + mc * 8];
    }
    return;
  }

  // ---- adjacency rows n0..n0+15 (MFMA hi/lo split) ----
  if (bx == 0 && tid < 256) flags[tid] = 0;   // split-K flag init (runs before k_gemm1)
  const int n0 = bx * 16;

  float a[8];
  {
    const float* e1p = &E1[(size_t)(n0 + lr) * EDIM + (lq & 1) * 8];
    *(float4*)&a[0] = *(const float4*)e1p;
    *(float4*)&a[4] = *(const float4*)(e1p + 4);
  }
  bf16x8 af1, af2;
#pragma unroll
  for (int j = 0; j < 8; j++) {
    unsigned short hs = f2bf(a[j]);
    af1[j] = (short)hs;
    float lo = a[j] - bf2f(hs);
    af2[j] = (lq < 2) ? (short)f2bf(lo) : (short)0;
  }

  float rs[4] = {0.f, 0.f, 0.f, 0.f};
  for (int t = wv; t < NSEN / 16; t += 8) {
    const int m = t * 16 + lr;
    float bv[8];
    const float* e2p = &E2[(size_t)m * EDIM + (lq & 1) * 8];
    *(float4*)&bv[0] = *(const float4*)e2p;
    *(float4*)&bv[4] = *(const float4*)(e2p + 4);
    bf16x8 bfrag;
#pragma unroll
    for (int j = 0; j < 8; j++) {
      unsigned short hs = f2bf(bv[j]);
      if (lq < 2) bfrag[j] = (short)hs;
      else        bfrag[j] = (short)f2bf(bv[j] - bf2f(hs));
    }
    f32x4 c = (f32x4){0.f, 0.f, 0.f, 0.f};
    c = __builtin_amdgcn_mfma_f32_16x16x32_bf16(af1, bfrag, c, 0, 0, 0);
    c = __builtin_amdgcn_mfma_f32_16x16x32_bf16(af2, bfrag, c, 0, 0, 0);
#pragma unroll
    for (int i = 0; i < 4; i++) {
      float p = __expf(fmaxf(c[i], 0.f));
      rs[i] += p;
      adjp[(size_t)(n0 + lq * 4 + i) * NP + t * 16 + lr] = f2bf(p);
    }
  }
  for (int i = tid; i < 16 * (NP - NSEN); i += 512) {
    int r = i / (NP - NSEN), c = i % (NP - NSEN);
    adjp[(size_t)(n0 + r) * NP + NSEN + c] = 0;
  }
#pragma unroll
  for (int i = 0; i < 4; i++) {
    rs[i] += __shfl_xor(rs[i], 1, 64);
    rs[i] += __shfl_xor(rs[i], 2, 64);
    rs[i] += __shfl_xor(rs[i], 4, 64);
    rs[i] += __shfl_xor(rs[i], 8, 64);
  }
  if (lr == 0) {
#pragma unroll
    for (int i = 0; i < 4; i++) rsum[wv][lq * 4 + i] = rs[i];
  }
  __syncthreads();
  if (tid < 16) {
    float s = 0.f;
#pragma unroll
    for (int w = 0; w < 8; w++) s += rsum[w][tid];
    rinv[n0 + tid] = 1.0f / s;
  }
}

// ---------------- Kernel 2: split-K GEMM with fused finish -----------------------
// K-loop unchanged from R8-R10 (785 TF proven). Epilogue: store bf16 partial ->
// threadfence -> atomic flag; second-arriving block loads partner partial, combines
// (both operands bf16-rounded -> deterministic), applies rinv+bias+relu, stores out.
__global__ __launch_bounds__(256, 2) void k_gemm1(const unsigned short* __restrict__ A,
                                                  const unsigned short* __restrict__ Bt,
                                                  unsigned short* __restrict__ part,
                                                  int* __restrict__ flags,
                                                  const float* __restrict__ rinv,
                                                  const float* __restrict__ bias,
                                                  float* __restrict__ out) {
  __shared__ __align__(16) unsigned short smem[32768];  // 64 KB: A 2x8192 | B 2x8192
  const int tid = threadIdx.x;
  const int lane = tid & 63, wv = tid >> 6;
  const int wr = wv >> 1, wc = wv & 1;     // 2 x 2 wave grid, wave tile 64x64
  const int lr = lane & 15, lq = lane >> 4;
  const int gx = blockIdx.x;               // 0..63 = 2*mtile + kh
  const int m0 = (gx >> 1) * 128;
  const int kb0 = (gx & 1) * 2048;
  const int b  = blockIdx.y;
  const int c0 = b * 128;
  unsigned short* tA0 = smem;            // 2 * 8192 shorts
  unsigned short* tB0 = smem + 16384;    // 2 * 8192 shorts

  f32x4 acc[4][4];
#pragma unroll
  for (int p = 0; p < 4; p++)
#pragma unroll
    for (int q = 0; q < 4; q++) acc[p][q] = (f32x4){0.f, 0.f, 0.f, 0.f};

#define STAGE(bufi, kb)                                                              \
  {                                                                                  \
    _Pragma("unroll")                                                                \
    for (int s = 0; s < 4; s++) {                                                    \
      int idx = s * 256 + tid;                                                       \
      int row = idx >> 3;                                                            \
      int kc = ((idx & 7) ^ (row & 7)) << 3;                                         \
      gl_lds16(&A[(size_t)(m0 + row) * NP + (kb) + kc], &tA0[(bufi)*8192 + idx*8]);  \
      gl_lds16(&Bt[(size_t)(c0 + row) * NP + (kb) + kc], &tB0[(bufi)*8192 + idx*8]); \
    }                                                                                \
  }

  STAGE(0, kb0);

  for (int it = 0; it < 32; ++it) {
    const int cur = it & 1;
    if (it < 31) {
      STAGE(cur ^ 1, kb0 + (it + 1) * 64);
      asm volatile("s_waitcnt vmcnt(8)" ::: "memory");
    } else {
      asm volatile("s_waitcnt vmcnt(0)" ::: "memory");
    }
    __builtin_amdgcn_s_barrier();

    bf16x8 af0[4], bf0[4], af1[4], bf1[4];
    {
      const int koff0 = (lq * 8) ^ ((lr & 7) << 3);
#pragma unroll
      for (int p = 0; p < 4; p++)
        af0[p] = *(const bf16x8*)&tA0[cur * 8192 + (wr * 64 + p * 16 + lr) * 64 + koff0];
#pragma unroll
      for (int q = 0; q < 4; q++)
        bf0[q] = *(const bf16x8*)&tB0[cur * 8192 + (wc * 64 + q * 16 + lr) * 64 + koff0];
    }
    __builtin_amdgcn_sched_barrier(0);
    {
      const int koff1 = (32 + lq * 8) ^ ((lr & 7) << 3);
#pragma unroll
      for (int p = 0; p < 4; p++)
        af1[p] = *(const bf16x8*)&tA0[cur * 8192 + (wr * 64 + p * 16 + lr) * 64 + koff1];
#pragma unroll
      for (int q = 0; q < 4; q++)
        bf1[q] = *(const bf16x8*)&tB0[cur * 8192 + (wc * 64 + q * 16 + lr) * 64 + koff1];
    }
    asm volatile("s_waitcnt lgkmcnt(8)" ::: "memory");
    __builtin_amdgcn_sched_barrier(0);
    __builtin_amdgcn_s_setprio(1);
#pragma unroll
    for (int p = 0; p < 4; p++)
#pragma unroll
      for (int q = 0; q < 4; q++)
        acc[p][q] = __builtin_amdgcn_mfma_f32_16x16x32_bf16(af0[p], bf0[q], acc[p][q], 0, 0, 0);
    asm volatile("s_waitcnt lgkmcnt(0)" ::: "memory");
    __builtin_amdgcn_sched_barrier(0);
#pragma unroll
    for (int p = 0; p < 4; p++)
#pragma unroll
      for (int q = 0; q < 4; q++)
        acc[p][q] = __builtin_amdgcn_mfma_f32_16x16x32_bf16(af1[p], bf1[q], acc[p][q], 0, 0, 0);
    __builtin_amdgcn_s_setprio(0);
    __builtin_amdgcn_s_barrier();
  }
#undef STAGE

  // ---- fused split-K finish ----
  const int kh = gx & 1;
  const int tileid = (gx >> 1) * BATCH + b;   // 0..255
  unsigned short* pdst = part + ((size_t)(kh * 256 + tileid)) * 16384;
#pragma unroll
  for (int p = 0; p < 4; p++)
#pragma unroll
    for (int q = 0; q < 4; q++) {
      const int col = wc * 64 + q * 16 + lr;
#pragma unroll
      for (int i = 0; i < 4; i++) {
        const int row = wr * 64 + p * 16 + lq * 4 + i;
        pdst[row * 128 + col] = f2bf(acc[p][q][i]);
      }
    }
  __threadfence();      // release: partial visible device-wide
  __syncthreads();      // all threads' stores+fences done before the flag
  __shared__ int oldv;
  if (tid == 0) oldv = atomicAdd(&flags[tileid], 1);
  __syncthreads();
  if (oldv == 0) return;          // first arriver: partner will finish
  __threadfence();                // acquire: see partner's partial

  const unsigned short* psrc = part + ((size_t)((kh ^ 1) * 256 + tileid)) * 16384;
#pragma unroll
  for (int p = 0; p < 4; p++) {
    float rv[4];
#pragma unroll
    for (int i = 0; i < 4; i++)
      rv[i] = rinv[m0 + wr * 64 + p * 16 + lq * 4 + i];
#pragma unroll
    for (int q = 0; q < 4; q++) {
      const int col = wc * 64 + q * 16 + lr;
      const float bb = bias[col];
#pragma unroll
      for (int i = 0; i < 4; i++) {
        const int row = wr * 64 + p * 16 + lq * 4 + i;
        const int n = m0 + row;
        if (n < NSEN) {
          // both operands bf16-rounded -> order-independent (deterministic)
          float v = (bf2f(f2bf(acc[p][q][i])) + bf2f(psrc[row * 128 + col])) * rv[i] + bb;
          out[((size_t)b * NSEN + n) * DOUT + col] = fmaxf(v, 0.f);
        }
      }
    }
  }
}

// ---------------- launch ---------------------------------------------------------
extern "C" void kernel_launch(void* const* d_in, const int* in_sizes, int n_in,
                              void* d_out, int out_size, void* d_ws, size_t ws_size,
                              hipStream_t stream) {
  const float* x    = (const float*)d_in[0];
  const float* E1   = (const float*)d_in[1];
  const float* E2   = (const float*)d_in[2];
  const float* W    = (const float*)d_in[3];
  const float* bias = (const float*)d_in[4];
  float* out = (float*)d_out;

  char* ws = (char*)d_ws;
  // layout: adjp 33554432 | yt 8388608 | rinv 16384 | flags 16384 | part 16777216 (~56 MiB)
  unsigned short* adjp = (unsigned short*)(ws);
  unsigned short* yt   = (unsigned short*)(ws + 33554432);
  float*          rinv = (float*)(ws + 33554432 + 8388608);
  int*            flags= (int*)(ws + 33554432 + 8388608 + 16384);
  unsigned short* part = (unsigned short*)(ws + 33554432 + 8388608 + 16384 + 16384);

  k_prep<<<dim3(506), dim3(512), 0, stream>>>(E1, E2, W, x, adjp, rinv, yt, flags);
  k_gemm1<<<dim3(64, BATCH), dim3(256), 0, stream>>>(adjp, yt, part, flags, rinv, bias, out);
}

// Round 12
// 81.750 us; speedup vs baseline: 2.3604x; 2.3604x over previous
//
#include <hip/hip_runtime.h>
#include <hip/hip_bf16.h>

#define NSEN 4000
#define NP   4096
#define DIN  128
#define DOUT 128
#define EDIM 16
#define BATCH 8

typedef __attribute__((ext_vector_type(8))) short bf16x8;
typedef __attribute__((ext_vector_type(4))) float f32x4;

__device__ __forceinline__ unsigned short f2bf(float f) {
  unsigned int u = __float_as_uint(f);
  unsigned int r = (u + 0x7FFFu + ((u >> 16) & 1u)) >> 16;
  return (unsigned short)r;
}
__device__ __forceinline__ float bf2f(unsigned short s) {
  unsigned int u = ((unsigned int)s) << 16;
  return __uint_as_float(u);
}

__device__ __forceinline__ void gl_lds16(const void* g, void* l) {
  __builtin_amdgcn_global_load_lds((const __attribute__((address_space(1))) void*)g,
                                   (__attribute__((address_space(3))) void*)l, 16, 0, 0);
}

// ---------------- Kernel 1 (merged prep) -----------------------------------------
// blocks 0..249:   P = exp(relu(E1 @ E2^T)) unnorm -> adjp bf16 (LDS-bounced,
//                  coalesced stores; K-pad cols zeroed) ; rinv = 1/rowsum
// blocks 250..505: yt[b*128+o][m] = bf16( (x @ W)[b,m,o] ), cols m>=NSEN -> 0
__global__ __launch_bounds__(512) void k_prep(const float* __restrict__ E1,
                                              const float* __restrict__ E2,
                                              const float* __restrict__ W,
                                              const float* __restrict__ x,
                                              unsigned short* __restrict__ adjp,
                                              float* __restrict__ rinv,
                                              unsigned short* __restrict__ yt) {
  __shared__ float rsum[8][16];
  __shared__ __align__(16) unsigned short pool[34816];  // 69.6 KB, branch-aliased
  const int bx = blockIdx.x;
  const int tid = threadIdx.x;
  const int lane = tid & 63, wv = tid >> 6;
  const int lr = lane & 15, lq = lane >> 4;

  if (bx >= 250) {
    unsigned short* wlds = pool;            // [128][136] W^T bf16
    unsigned short* ylds = pool + 17408;    // [128][136] y^T bf16
    // ---- stage W -> LDS as bf16 W^T (coalesced float4 reads, 8/thread) ----
    {
      const int fr = tid >> 5;   // 0..15
      const int o4 = tid & 31;   // 0..31
#pragma unroll
      for (int r8 = 0; r8 < 8; r8++) {
        const int f = fr + r8 * 16;
        float4 w4 = *(const float4*)&W[(size_t)f * DOUT + o4 * 4];
        wlds[(o4 * 4 + 0) * 136 + f] = f2bf(w4.x);
        wlds[(o4 * 4 + 1) * 136 + f] = f2bf(w4.y);
        wlds[(o4 * 4 + 2) * 136 + f] = f2bf(w4.z);
        wlds[(o4 * 4 + 3) * 136 + f] = f2bf(w4.w);
      }
    }
    __syncthreads();

    const int yi = bx - 250;        // 0..255
    const int b  = yi >> 5;         // 0..7
    const int m0 = (yi & 31) * 128; // 0..3968
    const int mh = wv >> 2;         // 0..1 : 64-m half
    const int os = wv & 3;          // 0..3 : 32-o strip

    bf16x8 af[2][4];
#pragma unroll
    for (int ot = 0; ot < 2; ot++) {
      const int ob = os * 32 + ot * 16 + lr;
#pragma unroll
      for (int ks = 0; ks < 4; ks++)
        af[ot][ks] = *(const bf16x8*)&wlds[ob * 136 + ks * 32 + lq * 8];
    }

#pragma unroll
    for (int mt = 0; mt < 4; mt++) {
      const int mloc = mh * 64 + mt * 16;
      const int m = m0 + mloc + lr;
      bf16x8 bx8[4];
      if (m < NSEN) {
        const float* xp = &x[((size_t)b * NSEN + m) * DIN + lq * 8];
#pragma unroll
        for (int ks = 0; ks < 4; ks++) {
          float4 v0 = *(const float4*)(xp + ks * 32);
          float4 v1 = *(const float4*)(xp + ks * 32 + 4);
          bx8[ks][0] = (short)f2bf(v0.x); bx8[ks][1] = (short)f2bf(v0.y);
          bx8[ks][2] = (short)f2bf(v0.z); bx8[ks][3] = (short)f2bf(v0.w);
          bx8[ks][4] = (short)f2bf(v1.x); bx8[ks][5] = (short)f2bf(v1.y);
          bx8[ks][6] = (short)f2bf(v1.z); bx8[ks][7] = (short)f2bf(v1.w);
        }
      } else {
#pragma unroll
        for (int ks = 0; ks < 4; ks++)
#pragma unroll
          for (int j = 0; j < 8; j++) bx8[ks][j] = 0;
      }
#pragma unroll
      for (int ot = 0; ot < 2; ot++) {
        f32x4 c = (f32x4){0.f, 0.f, 0.f, 0.f};
#pragma unroll
        for (int ks = 0; ks < 4; ks++)
          c = __builtin_amdgcn_mfma_f32_16x16x32_bf16(af[ot][ks], bx8[ks], c, 0, 0, 0);
#pragma unroll
        for (int i = 0; i < 4; i++)
          ylds[(os * 32 + ot * 16 + lq * 4 + i) * 136 + mloc + lr] = f2bf(c[i]);
      }
    }
    __syncthreads();
#pragma unroll
    for (int s2 = 0; s2 < 4; s2++) {
      int c = s2 * 512 + tid;
      int row = c >> 4;          // 0..127
      int mc = c & 15;           // 0..15
      *(bf16x8*)&yt[(size_t)(b * 128 + row) * NP + m0 + mc * 8] =
          *(const bf16x8*)&ylds[row * 136 + mc * 8];
    }
    return;
  }

  // ---- adjacency rows n0..n0+15 (MFMA hi/lo split), LDS-bounced stores ----
  unsigned short* bounce = pool;   // [16][1040] bf16 window buffer (33.3 KB)
  const int n0 = bx * 16;

  float a[8];
  {
    const float* e1p = &E1[(size_t)(n0 + lr) * EDIM + (lq & 1) * 8];
    *(float4*)&a[0] = *(const float4*)e1p;
    *(float4*)&a[4] = *(const float4*)(e1p + 4);
  }
  bf16x8 af1, af2;
#pragma unroll
  for (int j = 0; j < 8; j++) {
    unsigned short hs = f2bf(a[j]);
    af1[j] = (short)hs;
    float lo = a[j] - bf2f(hs);
    af2[j] = (lq < 2) ? (short)f2bf(lo) : (short)0;
  }

  float rs[4] = {0.f, 0.f, 0.f, 0.f};
  for (int w0 = 0; w0 < 256; w0 += 64) {   // 4 windows of 64 t-tiles (1024 cols)
    if (w0 == 192) {
      // zero the K-pad region (t 250..255 -> cols 4000..4095)
      for (int z = tid; z < 16 * 96; z += 512) {
        int zr = z / 96, zc = z % 96;
        bounce[zr * 1040 + 58 * 16 + zc] = 0;
      }
    }
    const int tend = (w0 + 64 < 250) ? (w0 + 64) : 250;
    for (int t = w0 + wv; t < tend; t += 8) {
      const int m = t * 16 + lr;
      float bv[8];
      const float* e2p = &E2[(size_t)m * EDIM + (lq & 1) * 8];
      *(float4*)&bv[0] = *(const float4*)e2p;
      *(float4*)&bv[4] = *(const float4*)(e2p + 4);
      bf16x8 bfrag;
#pragma unroll
      for (int j = 0; j < 8; j++) {
        unsigned short hs = f2bf(bv[j]);
        if (lq < 2) bfrag[j] = (short)hs;
        else        bfrag[j] = (short)f2bf(bv[j] - bf2f(hs));
      }
      f32x4 c = (f32x4){0.f, 0.f, 0.f, 0.f};
      c = __builtin_amdgcn_mfma_f32_16x16x32_bf16(af1, bfrag, c, 0, 0, 0);
      c = __builtin_amdgcn_mfma_f32_16x16x32_bf16(af2, bfrag, c, 0, 0, 0);
#pragma unroll
      for (int i = 0; i < 4; i++) {
        float p = __expf(fmaxf(c[i], 0.f));
        rs[i] += p;
        bounce[(lq * 4 + i) * 1040 + (t - w0) * 16 + lr] = f2bf(p);
      }
    }
    __syncthreads();
    // coalesced flush: 16 rows x 128 bf16x8 chunks = 2048 chunks, 4/thread
#pragma unroll
    for (int s2 = 0; s2 < 4; s2++) {
      int cch = s2 * 512 + tid;
      int row = cch >> 7, mc = cch & 127;
      *(bf16x8*)&adjp[(size_t)(n0 + row) * NP + w0 * 16 + mc * 8] =
          *(const bf16x8*)&bounce[row * 1040 + mc * 8];
    }
    __syncthreads();
  }
#pragma unroll
  for (int i = 0; i < 4; i++) {
    rs[i] += __shfl_xor(rs[i], 1, 64);
    rs[i] += __shfl_xor(rs[i], 2, 64);
    rs[i] += __shfl_xor(rs[i], 4, 64);
    rs[i] += __shfl_xor(rs[i], 8, 64);
  }
  if (lr == 0) {
#pragma unroll
    for (int i = 0; i < 4; i++) rsum[wv][lq * 4 + i] = rs[i];
  }
  __syncthreads();
  if (tid < 16) {
    float s = 0.f;
#pragma unroll
    for (int w = 0; w < 8; w++) s += rsum[w][tid];
    rinv[n0 + tid] = 1.0f / s;
  }
}

// ---------------- Kernel 2: 256x256-tile split-K GEMM  C = P @ yt^T --------------
// One logical GEMM M=4096, N=1024 (batch = column blocks), K=4096.
// 8 waves (2M x 4N), wave tile 128x64 -> 0.375 KB LDS-read per MFMA (vs 0.5 before).
// 128 KB LDS double-buffered BK=64; depth-1 counted vmcnt(8); split lgkmcnt per
// k-slice; setprio; proven XOR swizzle. grid ((KS*16), 4): gid%8 = mt%8 -> the 4
// nt-blocks of each A-panel chunk share an XCD.
__global__ __launch_bounds__(512, 2) void k_gemm(const unsigned short* __restrict__ A,
                                                 const unsigned short* __restrict__ Bt,
                                                 unsigned short* __restrict__ part,
                                                 int nsteps) {
  __shared__ __align__(16) unsigned short smem[65536];  // 128 KB
  unsigned short* tA0 = smem;           // 2 x 16384 shorts
  unsigned short* tB0 = smem + 32768;   // 2 x 16384 shorts
  const int tid = threadIdx.x;
  const int lane = tid & 63, wv = tid >> 6;
  const int wr = wv >> 2, wcn = wv & 3;   // 2M x 4N waves, wave tile 128x64
  const int lr = lane & 15, lq = lane >> 4;
  const int kh = blockIdx.x >> 4;
  const int m0 = (blockIdx.x & 15) * 256;
  const int n0c = blockIdx.y * 256;
  const int kb0 = kh * nsteps * 64;

  f32x4 acc[8][4];
#pragma unroll
  for (int p = 0; p < 8; p++)
#pragma unroll
    for (int q = 0; q < 4; q++) acc[p][q] = (f32x4){0.f, 0.f, 0.f, 0.f};

  // 8 gl_lds16 per thread per STAGE (4 A + 4 B); source k-chunk pre-swizzled
#define STAGE(bufi, kb)                                                                 \
  {                                                                                     \
    _Pragma("unroll")                                                                   \
    for (int s = 0; s < 4; s++) {                                                       \
      int idx = s * 512 + tid;                                                          \
      int row = idx >> 3;                                                               \
      int kc = ((idx & 7) ^ (row & 7)) << 3;                                            \
      gl_lds16(&A[(size_t)(m0 + row) * NP + (kb) + kc], &tA0[(bufi)*16384 + idx*8]);    \
      gl_lds16(&Bt[(size_t)(n0c + row) * NP + (kb) + kc], &tB0[(bufi)*16384 + idx*8]);  \
    }                                                                                   \
  }

  STAGE(0, kb0);

  for (int it = 0; it < nsteps; ++it) {
    const int cur = it & 1;
    if (it < nsteps - 1) {
      STAGE(cur ^ 1, kb0 + (it + 1) * 64);
      asm volatile("s_waitcnt vmcnt(8)" ::: "memory");  // cur's 8 landed; next 8 in flight
    } else {
      asm volatile("s_waitcnt vmcnt(0)" ::: "memory");
    }
    __builtin_amdgcn_s_barrier();

    {  // k-slice 0
      const int koff = (lq * 8) ^ ((lr & 7) << 3);
      bf16x8 af[8], bf[4];
#pragma unroll
      for (int p = 0; p < 8; p++)
        af[p] = *(const bf16x8*)&tA0[cur * 16384 + (wr * 128 + p * 16 + lr) * 64 + koff];
#pragma unroll
      for (int q = 0; q < 4; q++)
        bf[q] = *(const bf16x8*)&tB0[cur * 16384 + (wcn * 64 + q * 16 + lr) * 64 + koff];
      asm volatile("s_waitcnt lgkmcnt(0)" ::: "memory");
      __builtin_amdgcn_sched_barrier(0);
      __builtin_amdgcn_s_setprio(1);
#pragma unroll
      for (int p = 0; p < 8; p++)
#pragma unroll
        for (int q = 0; q < 4; q++)
          acc[p][q] = __builtin_amdgcn_mfma_f32_16x16x32_bf16(af[p], bf[q], acc[p][q], 0, 0, 0);
      __builtin_amdgcn_s_setprio(0);
    }
    {  // k-slice 1
      const int koff = (32 + lq * 8) ^ ((lr & 7) << 3);
      bf16x8 af[8], bf[4];
#pragma unroll
      for (int p = 0; p < 8; p++)
        af[p] = *(const bf16x8*)&tA0[cur * 16384 + (wr * 128 + p * 16 + lr) * 64 + koff];
#pragma unroll
      for (int q = 0; q < 4; q++)
        bf[q] = *(const bf16x8*)&tB0[cur * 16384 + (wcn * 64 + q * 16 + lr) * 64 + koff];
      asm volatile("s_waitcnt lgkmcnt(0)" ::: "memory");
      __builtin_amdgcn_sched_barrier(0);
      __builtin_amdgcn_s_setprio(1);
#pragma unroll
      for (int p = 0; p < 8; p++)
#pragma unroll
        for (int q = 0; q < 4; q++)
          acc[p][q] = __builtin_amdgcn_mfma_f32_16x16x32_bf16(af[p], bf[q], acc[p][q], 0, 0, 0);
      __builtin_amdgcn_s_setprio(0);
    }
    __builtin_amdgcn_s_barrier();  // all reads of cur done -> reusable
  }
#undef STAGE

  // epilogue: bf16 partial store part[kh][m][j]
  unsigned short* pdst = part + ((size_t)kh << 22);  // kh * 4096*1024
#pragma unroll
  for (int p = 0; p < 8; p++)
#pragma unroll
    for (int q = 0; q < 4; q++) {
      const int col = n0c + wcn * 64 + q * 16 + lr;
#pragma unroll
      for (int i = 0; i < 4; i++) {
        const int row = m0 + wr * 128 + p * 16 + lq * 4 + i;
        pdst[(size_t)row * 1024 + col] = f2bf(acc[p][q][i]);
      }
    }
}

// ---------------- Kernel 3: out = relu((sum_kh part[kh])*rinv + bias) ------------
__global__ __launch_bounds__(256) void k_fin(const unsigned short* __restrict__ part,
                                             const float* __restrict__ rinv,
                                             const float* __restrict__ bias,
                                             float* __restrict__ out, int ksl) {
  const int tid = threadIdx.x;
  const int nl = tid >> 4;        // 0..15 row within block
  const int ch = tid & 15;        // 0..15 chunk of 8 outputs
  const int n  = blockIdx.x * 16 + nl;   // < 4000
  const int b  = blockIdx.y;
  const int j  = b * 128 + ch * 8;

  float s[8] = {0.f, 0.f, 0.f, 0.f, 0.f, 0.f, 0.f, 0.f};
  for (int kh = 0; kh < ksl; kh++) {
    bf16x8 pv = *(const bf16x8*)&part[((size_t)kh << 22) + (size_t)n * 1024 + j];
#pragma unroll
    for (int jj = 0; jj < 8; jj++) s[jj] += bf2f((unsigned short)pv[jj]);
  }
  const float rv = rinv[n];
  float4 bb0 = *(const float4*)&bias[ch * 8];
  float4 bb1 = *(const float4*)&bias[ch * 8 + 4];
  float r[8];
#pragma unroll
  for (int jj = 0; jj < 8; jj++) {
    float bbj = (jj < 4) ? ((const float*)&bb0)[jj] : ((const float*)&bb1)[jj - 4];
    r[jj] = fmaxf(s[jj] * rv + bbj, 0.f);
  }
  float* op = &out[((size_t)b * NSEN + n) * DOUT + ch * 8];
  *(float4*)op       = make_float4(r[0], r[1], r[2], r[3]);
  *(float4*)(op + 4) = make_float4(r[4], r[5], r[6], r[7]);
}

// ---------------- launch ---------------------------------------------------------
extern "C" void kernel_launch(void* const* d_in, const int* in_sizes, int n_in,
                              void* d_out, int out_size, void* d_ws, size_t ws_size,
                              hipStream_t stream) {
  const float* x    = (const float*)d_in[0];
  const float* E1   = (const float*)d_in[1];
  const float* E2   = (const float*)d_in[2];
  const float* W    = (const float*)d_in[3];
  const float* bias = (const float*)d_in[4];
  float* out = (float*)d_out;

  char* ws = (char*)d_ws;
  // layout: adjp 33554432 | yt 8388608 | rinv 16384 | part KS*8388608
  unsigned short* adjp = (unsigned short*)(ws);
  unsigned short* yt   = (unsigned short*)(ws + 33554432);
  float*          rinv = (float*)(ws + 33554432 + 8388608);
  unsigned short* part = (unsigned short*)(ws + 33554432 + 8388608 + 16384);

  const size_t need4 = 33554432ull + 8388608 + 16384 + 4ull * 8388608;
  const int KS = (ws_size >= need4) ? 4 : 2;   // split-K factor (ws poison shows ~268MB, so 4)
  const int nsteps = 64 / KS;

  k_prep<<<dim3(506), dim3(512), 0, stream>>>(E1, E2, W, x, adjp, rinv, yt);
  k_gemm<<<dim3(KS * 16, 4), dim3(512), 0, stream>>>(adjp, yt, part, nsteps);
  k_fin<<<dim3(250, BATCH), dim3(256), 0, stream>>>(part, rinv, bias, out, KS);
}

// Round 13
// 79.279 us; speedup vs baseline: 2.4340x; 1.0312x over previous
//
#include <hip/hip_runtime.h>
#include <hip/hip_bf16.h>

#define NSEN 4000
#define NP   4096
#define DIN  128
#define DOUT 128
#define EDIM 16
#define BATCH 8

typedef __attribute__((ext_vector_type(8))) short bf16x8;
typedef __attribute__((ext_vector_type(4))) float f32x4;

__device__ __forceinline__ unsigned short f2bf(float f) {
  unsigned int u = __float_as_uint(f);
  unsigned int r = (u + 0x7FFFu + ((u >> 16) & 1u)) >> 16;
  return (unsigned short)r;
}
__device__ __forceinline__ float bf2f(unsigned short s) {
  unsigned int u = ((unsigned int)s) << 16;
  return __uint_as_float(u);
}

__device__ __forceinline__ void gl_lds16(const void* g, void* l) {
  __builtin_amdgcn_global_load_lds((const __attribute__((address_space(1))) void*)g,
                                   (__attribute__((address_space(3))) void*)l, 16, 0, 0);
}

// ---------------- Kernel 1 (merged prep) -----------------------------------------
// blocks 0..249:   P = exp(relu(E1 @ E2^T)) unnorm -> adjp bf16 ; rinv = 1/rowsum
//                  (direct stores — R10-proven form)
// blocks 250..505: yt[b*128+o][m] = bf16( (x @ W)[b,m,o] ), cols m>=NSEN -> 0
__global__ __launch_bounds__(512) void k_prep(const float* __restrict__ E1,
                                              const float* __restrict__ E2,
                                              const float* __restrict__ W,
                                              const float* __restrict__ x,
                                              unsigned short* __restrict__ adjp,
                                              float* __restrict__ rinv,
                                              unsigned short* __restrict__ yt) {
  __shared__ float rsum[8][16];
  __shared__ __align__(16) unsigned short pool[34816];  // y-branch: wlds+ylds
  const int bx = blockIdx.x;
  const int tid = threadIdx.x;
  const int lane = tid & 63, wv = tid >> 6;
  const int lr = lane & 15, lq = lane >> 4;

  if (bx >= 250) {
    unsigned short* wlds = pool;            // [128][136] W^T bf16
    unsigned short* ylds = pool + 17408;    // [128][136] y^T bf16
    {
      const int fr = tid >> 5;   // 0..15
      const int o4 = tid & 31;   // 0..31
#pragma unroll
      for (int r8 = 0; r8 < 8; r8++) {
        const int f = fr + r8 * 16;
        float4 w4 = *(const float4*)&W[(size_t)f * DOUT + o4 * 4];
        wlds[(o4 * 4 + 0) * 136 + f] = f2bf(w4.x);
        wlds[(o4 * 4 + 1) * 136 + f] = f2bf(w4.y);
        wlds[(o4 * 4 + 2) * 136 + f] = f2bf(w4.z);
        wlds[(o4 * 4 + 3) * 136 + f] = f2bf(w4.w);
      }
    }
    __syncthreads();

    const int yi = bx - 250;        // 0..255
    const int b  = yi >> 5;         // 0..7
    const int m0 = (yi & 31) * 128; // 0..3968
    const int mh = wv >> 2;         // 0..1 : 64-m half
    const int os = wv & 3;          // 0..3 : 32-o strip

    bf16x8 af[2][4];
#pragma unroll
    for (int ot = 0; ot < 2; ot++) {
      const int ob = os * 32 + ot * 16 + lr;
#pragma unroll
      for (int ks = 0; ks < 4; ks++)
        af[ot][ks] = *(const bf16x8*)&wlds[ob * 136 + ks * 32 + lq * 8];
    }

#pragma unroll
    for (int mt = 0; mt < 4; mt++) {
      const int mloc = mh * 64 + mt * 16;
      const int m = m0 + mloc + lr;
      bf16x8 bx8[4];
      if (m < NSEN) {
        const float* xp = &x[((size_t)b * NSEN + m) * DIN + lq * 8];
#pragma unroll
        for (int ks = 0; ks < 4; ks++) {
          float4 v0 = *(const float4*)(xp + ks * 32);
          float4 v1 = *(const float4*)(xp + ks * 32 + 4);
          bx8[ks][0] = (short)f2bf(v0.x); bx8[ks][1] = (short)f2bf(v0.y);
          bx8[ks][2] = (short)f2bf(v0.z); bx8[ks][3] = (short)f2bf(v0.w);
          bx8[ks][4] = (short)f2bf(v1.x); bx8[ks][5] = (short)f2bf(v1.y);
          bx8[ks][6] = (short)f2bf(v1.z); bx8[ks][7] = (short)f2bf(v1.w);
        }
      } else {
#pragma unroll
        for (int ks = 0; ks < 4; ks++)
#pragma unroll
          for (int j = 0; j < 8; j++) bx8[ks][j] = 0;
      }
#pragma unroll
      for (int ot = 0; ot < 2; ot++) {
        f32x4 c = (f32x4){0.f, 0.f, 0.f, 0.f};
#pragma unroll
        for (int ks = 0; ks < 4; ks++)
          c = __builtin_amdgcn_mfma_f32_16x16x32_bf16(af[ot][ks], bx8[ks], c, 0, 0, 0);
#pragma unroll
        for (int i = 0; i < 4; i++)
          ylds[(os * 32 + ot * 16 + lq * 4 + i) * 136 + mloc + lr] = f2bf(c[i]);
      }
    }
    __syncthreads();
#pragma unroll
    for (int s2 = 0; s2 < 4; s2++) {
      int c = s2 * 512 + tid;
      int row = c >> 4;          // 0..127
      int mc = c & 15;           // 0..15
      *(bf16x8*)&yt[(size_t)(b * 128 + row) * NP + m0 + mc * 8] =
          *(const bf16x8*)&ylds[row * 136 + mc * 8];
    }
    return;
  }

  // ---- adjacency rows n0..n0+15 (MFMA hi/lo split, direct stores) ----
  const int n0 = bx * 16;

  float a[8];
  {
    const float* e1p = &E1[(size_t)(n0 + lr) * EDIM + (lq & 1) * 8];
    *(float4*)&a[0] = *(const float4*)e1p;
    *(float4*)&a[4] = *(const float4*)(e1p + 4);
  }
  bf16x8 af1, af2;
#pragma unroll
  for (int j = 0; j < 8; j++) {
    unsigned short hs = f2bf(a[j]);
    af1[j] = (short)hs;
    float lo = a[j] - bf2f(hs);
    af2[j] = (lq < 2) ? (short)f2bf(lo) : (short)0;
  }

  float rs[4] = {0.f, 0.f, 0.f, 0.f};
  for (int t = wv; t < NSEN / 16; t += 8) {
    const int m = t * 16 + lr;
    float bv[8];
    const float* e2p = &E2[(size_t)m * EDIM + (lq & 1) * 8];
    *(float4*)&bv[0] = *(const float4*)e2p;
    *(float4*)&bv[4] = *(const float4*)(e2p + 4);
    bf16x8 bfrag;
#pragma unroll
    for (int j = 0; j < 8; j++) {
      unsigned short hs = f2bf(bv[j]);
      if (lq < 2) bfrag[j] = (short)hs;
      else        bfrag[j] = (short)f2bf(bv[j] - bf2f(hs));
    }
    f32x4 c = (f32x4){0.f, 0.f, 0.f, 0.f};
    c = __builtin_amdgcn_mfma_f32_16x16x32_bf16(af1, bfrag, c, 0, 0, 0);
    c = __builtin_amdgcn_mfma_f32_16x16x32_bf16(af2, bfrag, c, 0, 0, 0);
#pragma unroll
    for (int i = 0; i < 4; i++) {
      float p = __expf(fmaxf(c[i], 0.f));
      rs[i] += p;
      adjp[(size_t)(n0 + lq * 4 + i) * NP + t * 16 + lr] = f2bf(p);
    }
  }
  for (int i = tid; i < 16 * (NP - NSEN); i += 512) {
    int r = i / (NP - NSEN), c = i % (NP - NSEN);
    adjp[(size_t)(n0 + r) * NP + NSEN + c] = 0;
  }
#pragma unroll
  for (int i = 0; i < 4; i++) {
    rs[i] += __shfl_xor(rs[i], 1, 64);
    rs[i] += __shfl_xor(rs[i], 2, 64);
    rs[i] += __shfl_xor(rs[i], 4, 64);
    rs[i] += __shfl_xor(rs[i], 8, 64);
  }
  if (lr == 0) {
#pragma unroll
    for (int i = 0; i < 4; i++) rsum[wv][lq * 4 + i] = rs[i];
  }
  __syncthreads();
  if (tid < 16) {
    float s = 0.f;
#pragma unroll
    for (int w = 0; w < 8; w++) s += rsum[w][tid];
    rinv[n0 + tid] = 1.0f / s;
  }
}

// ---------------- Kernel 2: 256x256-tile split-K GEMM, m201-style phase schedule --
// 8 waves (2M x 4N), wave tile 128x64. BK=64, 128 KB dbuf LDS. Each K-tile = 4
// sub-phases: {2 gl_lds || 4-8 ds_read -> barrier -> lgkmcnt(0) -> setprio(1) ->
// 16 MFMA -> setprio(0) -> barrier}. Staging spread per-phase; vmcnt counted (2),
// never drained mid-loop. Proven XOR swizzle; XCD-bijective grid.
__global__ __launch_bounds__(512, 2) void k_gemm(const unsigned short* __restrict__ A,
                                                 const unsigned short* __restrict__ Bt,
                                                 unsigned short* __restrict__ part,
                                                 int nsteps) {
  __shared__ __align__(16) unsigned short smem[65536];  // 128 KB
  unsigned short* tA0 = smem;           // 2 x 16384 shorts
  unsigned short* tB0 = smem + 32768;   // 2 x 16384 shorts
  const int tid = threadIdx.x;
  const int lane = tid & 63, wv = tid >> 6;
  const int wr = wv >> 2, wcn = wv & 3;   // 2M x 4N waves, wave tile 128x64
  const int lr = lane & 15, lq = lane >> 4;
  const int kh = blockIdx.x >> 4;
  const int m0 = (blockIdx.x & 15) * 256;
  const int n0c = blockIdx.y * 256;
  const int kb0 = kh * nsteps * 64;

  f32x4 acc[8][4];
#pragma unroll
  for (int p = 0; p < 8; p++)
#pragma unroll
    for (int q = 0; q < 4; q++) acc[p][q] = (f32x4){0.f, 0.f, 0.f, 0.f};

  // one 16B A-chunk + one 16B B-chunk per thread per sub-phase (s = 0..3)
#define STAGE2(bufi, kb, s)                                                             \
  {                                                                                     \
    int idx = (s) * 512 + tid;                                                          \
    int row = idx >> 3;                                                                 \
    int kc = ((idx & 7) ^ (row & 7)) << 3;                                              \
    gl_lds16(&A[(size_t)(m0 + row) * NP + (kb) + kc], &tA0[(bufi)*16384 + idx*8]);      \
    gl_lds16(&Bt[(size_t)(n0c + row) * NP + (kb) + kc], &tB0[(bufi)*16384 + idx*8]);    \
  }

  // prologue: stage tile 0 fully
  STAGE2(0, kb0, 0); STAGE2(0, kb0, 1); STAGE2(0, kb0, 2); STAGE2(0, kb0, 3);

  for (int it = 0; it < nsteps; ++it) {
    const int cur = it & 1;
    const int nxt = cur ^ 1;
    const int kbn = kb0 + (it + 1) * 64;
    const bool pf = (it < nsteps - 1);
    bf16x8 bf[4];

#pragma unroll
    for (int ks = 0; ks < 2; ks++) {
      // ---- sub-phase (ks,0): A p0-3 + B q0-3, MFMA quadrant ----
      if (ks == 0) {
        if (pf) STAGE2(nxt, kbn, 0);
        if (it == 0) { asm volatile("s_waitcnt vmcnt(0)" ::: "memory"); }
        else if (pf) { asm volatile("s_waitcnt vmcnt(2)" ::: "memory"); }
        else         { asm volatile("s_waitcnt vmcnt(0)" ::: "memory"); }
        __builtin_amdgcn_s_barrier();
      } else {
        if (pf) STAGE2(nxt, kbn, 2);
      }
      {
        const int koff = (ks * 32 + lq * 8) ^ ((lr & 7) << 3);
        bf16x8 af[4];
#pragma unroll
        for (int p = 0; p < 4; p++)
          af[p] = *(const bf16x8*)&tA0[cur * 16384 + (wr * 128 + p * 16 + lr) * 64 + koff];
#pragma unroll
        for (int q = 0; q < 4; q++)
          bf[q] = *(const bf16x8*)&tB0[cur * 16384 + (wcn * 64 + q * 16 + lr) * 64 + koff];
        if (ks == 1) __builtin_amdgcn_s_barrier();
        asm volatile("s_waitcnt lgkmcnt(0)" ::: "memory");
        __builtin_amdgcn_sched_barrier(0);
        __builtin_amdgcn_s_setprio(1);
#pragma unroll
        for (int p = 0; p < 4; p++)
#pragma unroll
          for (int q = 0; q < 4; q++)
            acc[p][q] = __builtin_amdgcn_mfma_f32_16x16x32_bf16(af[p], bf[q], acc[p][q], 0, 0, 0);
        __builtin_amdgcn_s_setprio(0);
        __builtin_amdgcn_s_barrier();
      }
      // ---- sub-phase (ks,1): A p4-7, MFMA quadrant (B reused) ----
      {
        if (pf) STAGE2(nxt, kbn, (ks == 0) ? 1 : 3);
        const int koff = (ks * 32 + lq * 8) ^ ((lr & 7) << 3);
        bf16x8 af[4];
#pragma unroll
        for (int p = 0; p < 4; p++)
          af[p] = *(const bf16x8*)&tA0[cur * 16384 + (wr * 128 + (4 + p) * 16 + lr) * 64 + koff];
        __builtin_amdgcn_s_barrier();
        asm volatile("s_waitcnt lgkmcnt(0)" ::: "memory");
        __builtin_amdgcn_sched_barrier(0);
        __builtin_amdgcn_s_setprio(1);
#pragma unroll
        for (int p = 0; p < 4; p++)
#pragma unroll
          for (int q = 0; q < 4; q++)
            acc[4 + p][q] = __builtin_amdgcn_mfma_f32_16x16x32_bf16(af[p], bf[q], acc[4 + p][q], 0, 0, 0);
        __builtin_amdgcn_s_setprio(0);
        __builtin_amdgcn_s_barrier();
      }
    }
  }
#undef STAGE2

  // epilogue: bf16 partial store part[kh][m][j]
  unsigned short* pdst = part + ((size_t)kh << 22);  // kh * 4096*1024
#pragma unroll
  for (int p = 0; p < 8; p++)
#pragma unroll
    for (int q = 0; q < 4; q++) {
      const int col = n0c + wcn * 64 + q * 16 + lr;
#pragma unroll
      for (int i = 0; i < 4; i++) {
        const int row = m0 + wr * 128 + p * 16 + lq * 4 + i;
        pdst[(size_t)row * 1024 + col] = f2bf(acc[p][q][i]);
      }
    }
}

// ---------------- Kernel 3: out = relu((sum_kh part[kh])*rinv + bias) ------------
__global__ __launch_bounds__(256) void k_fin(const unsigned short* __restrict__ part,
                                             const float* __restrict__ rinv,
                                             const float* __restrict__ bias,
                                             float* __restrict__ out, int ksl) {
  const int tid = threadIdx.x;
  const int nl = tid >> 4;        // 0..15 row within block
  const int ch = tid & 15;        // 0..15 chunk of 8 outputs
  const int n  = blockIdx.x * 16 + nl;   // < 4000
  const int b  = blockIdx.y;
  const int j  = b * 128 + ch * 8;

  float s[8] = {0.f, 0.f, 0.f, 0.f, 0.f, 0.f, 0.f, 0.f};
  for (int kh = 0; kh < ksl; kh++) {
    bf16x8 pv = *(const bf16x8*)&part[((size_t)kh << 22) + (size_t)n * 1024 + j];
#pragma unroll
    for (int jj = 0; jj < 8; jj++) s[jj] += bf2f((unsigned short)pv[jj]);
  }
  const float rv = rinv[n];
  float4 bb0 = *(const float4*)&bias[ch * 8];
  float4 bb1 = *(const float4*)&bias[ch * 8 + 4];
  float r[8];
#pragma unroll
  for (int jj = 0; jj < 8; jj++) {
    float bbj = (jj < 4) ? ((const float*)&bb0)[jj] : ((const float*)&bb1)[jj - 4];
    r[jj] = fmaxf(s[jj] * rv + bbj, 0.f);
  }
  float* op = &out[((size_t)b * NSEN + n) * DOUT + ch * 8];
  *(float4*)op       = make_float4(r[0], r[1], r[2], r[3]);
  *(float4*)(op + 4) = make_float4(r[4], r[5], r[6], r[7]);
}

// ---------------- launch ---------------------------------------------------------
extern "C" void kernel_launch(void* const* d_in, const int* in_sizes, int n_in,
                              void* d_out, int out_size, void* d_ws, size_t ws_size,
                              hipStream_t stream) {
  const float* x    = (const float*)d_in[0];
  const float* E1   = (const float*)d_in[1];
  const float* E2   = (const float*)d_in[2];
  const float* W    = (const float*)d_in[3];
  const float* bias = (const float*)d_in[4];
  float* out = (float*)d_out;

  char* ws = (char*)d_ws;
  // layout: adjp 33554432 | yt 8388608 | rinv 16384 | part KS*8388608
  unsigned short* adjp = (unsigned short*)(ws);
  unsigned short* yt   = (unsigned short*)(ws + 33554432);
  float*          rinv = (float*)(ws + 33554432 + 8388608);
  unsigned short* part = (unsigned short*)(ws + 33554432 + 8388608 + 16384);

  const size_t need4 = 33554432ull + 8388608 + 16384 + 4ull * 8388608;
  const int KS = (ws_size >= need4) ? 4 : 2;
  const int nsteps = 64 / KS;

  k_prep<<<dim3(506), dim3(512), 0, stream>>>(E1, E2, W, x, adjp, rinv, yt);
  k_gemm<<<dim3(KS * 16, 4), dim3(512), 0, stream>>>(adjp, yt, part, nsteps);
  k_fin<<<dim3(250, BATCH), dim3(256), 0, stream>>>(part, rinv, bias, out, KS);
}